// Round 11
// baseline (141.238 us; speedup 1.0000x reference)
//
#include <hip/hip_runtime.h>
#include <math.h>

#define BB 4
#define NN 2048
#define FF 128
#define HH 4
#define DD 32
#define NEG_SLOPE 0.2f
#define LOG2E 1.4426950408889634f

typedef __attribute__((ext_vector_type(8))) short short8;
typedef __attribute__((ext_vector_type(4))) float floatx4;
typedef __attribute__((ext_vector_type(2))) float floatx2;

__device__ __forceinline__ float exp2_fast(float x) {
#if __has_builtin(__builtin_amdgcn_exp2f)
    return __builtin_amdgcn_exp2f(x);
#else
    return exp2f(x);
#endif
}

__device__ __forceinline__ int bit_mask(unsigned int w, int bit) {
#if __has_builtin(__builtin_amdgcn_sbfe)
    return __builtin_amdgcn_sbfe((int)w, bit, 1);    // v_bfe_i32: 0 or -1
#else
    return ((int)(w << (31 - bit))) >> 31;
#endif
}

__device__ __forceinline__ unsigned short to_bf16(float f) {
    unsigned int ui = __float_as_uint(f);
    ui += 0x7FFFu + ((ui >> 16) & 1u);   // RTNE
    return (unsigned short)(ui >> 16);
}

// pack two fp32 -> one u32 holding (bf16(hi)<<16 | bf16(lo)), RTNE
__device__ __forceinline__ unsigned int pack2_rtne(float lo, float hi) {
    unsigned int ul = __float_as_uint(lo); ul += 0x7FFFu + ((ul >> 16) & 1u);
    unsigned int uh = __float_as_uint(hi); uh += 0x7FFFu + ((uh >> 16) & 1u);
    return (ul >> 16) | (uh & 0xFFFF0000u);
}

// ---------------- K1: prep = {MFMA gemm_fused (blocks 0..511), pack_adj (512..1023)}
__global__ __launch_bounds__(256) void k_prep(const float* __restrict__ x,
                                              const float* __restrict__ W,
                                              const float* __restrict__ a_src,
                                              const float* __restrict__ a_dst,
                                              const int* __restrict__ adj,
                                              unsigned short* __restrict__ ht,
                                              float* __restrict__ es_t,
                                              float* __restrict__ ed_t,
                                              unsigned int* __restrict__ bits) {
    __shared__ unsigned short wbf[128][144];   // 36.9 KB, W as bf16 [o][i]
    __shared__ unsigned short hbf[128][24];    // 6 KB, h^T as bf16 [o][m_local]
    __shared__ float vs_s[HH][FF], vd_s[HH][FF];   // 4 KB
    __shared__ float as_s[FF], ad_s[FF];           // 1 KB
    int t = threadIdx.x;

    if (blockIdx.x >= 512) {
        // ---- pack_adj ----
        int idx = (blockIdx.x - 512) * 256 + t;
        int n = idx >> 6, w = idx & 63;
        const int4* base = (const int4*)(adj + (size_t)n * NN + w * 32);
        unsigned int word = 0;
#pragma unroll
        for (int q = 0; q < 8; ++q) {
            int4 a = base[q];
            word |= ((unsigned int)(a.x & 1)) << (q * 4 + 0);
            word |= ((unsigned int)(a.y & 1)) << (q * 4 + 1);
            word |= ((unsigned int)(a.z & 1)) << (q * 4 + 2);
            word |= ((unsigned int)(a.w & 1)) << (q * 4 + 3);
        }
        bits[idx] = word;
        return;
    }

    int m0g = blockIdx.x * 16;
    int b = m0g >> 11;
    int m_block = m0g & 2047;

    if (t < FF) { as_s[t] = a_src[t]; ad_s[t] = a_dst[t]; }
    // stage W -> bf16 LDS: 2048 chunks of 8 shorts
#pragma unroll
    for (int k = 0; k < 8; ++k) {
        int idx = t + k * 256;
        int row = idx >> 4, ch = idx & 15;
        const float* wp = W + (size_t)row * FF + ch * 8;
        float4 v0 = *(const float4*)wp;
        float4 v1 = *(const float4*)(wp + 4);
        unsigned int u[4];
        u[0] = pack2_rtne(v0.x, v0.y); u[1] = pack2_rtne(v0.z, v0.w);
        u[2] = pack2_rtne(v1.x, v1.y); u[3] = pack2_rtne(v1.z, v1.w);
        *(int4*)&wbf[row][ch * 8] = *(const int4*)u;
    }
    __syncthreads();

    // per-head column sums: vs[h][i] = sum_d W[h*32+d][i]*a_src[h][d]
    {
        int i = t & 127;
        float acc4[4] = {0.f, 0.f, 0.f, 0.f};
        if (t < 128) {
            for (int o = 0; o < 128; ++o) {
                float wv = __uint_as_float(((unsigned int)wbf[o][i]) << 16);
                acc4[o >> 5] += wv * as_s[o];
            }
#pragma unroll
            for (int hd = 0; hd < 4; ++hd) vs_s[hd][i] = acc4[hd];
        } else {
            for (int o = 0; o < 128; ++o) {
                float wv = __uint_as_float(((unsigned int)wbf[o][i]) << 16);
                acc4[o >> 5] += wv * ad_s[o];
            }
#pragma unroll
            for (int hd = 0; hd < 4; ++hd) vd_s[hd][i] = acc4[hd];
        }
    }

    // MFMA: h[m0g..+15][0..127]
    int wid = t >> 6, lane = t & 63;
    int r = lane & 15, q = lane >> 4;
    floatx4 acc[2] = {{0.f,0.f,0.f,0.f},{0.f,0.f,0.f,0.f}};
    const float* xrow = x + (size_t)(m0g + r) * FF + q * 8;
#pragma unroll
    for (int kk = 0; kk < 4; ++kk) {
        float4 a0 = *(const float4*)(xrow + kk * 32);
        float4 a1 = *(const float4*)(xrow + kk * 32 + 4);
        union { short8 s8; unsigned int u[4]; } af;
        af.u[0] = pack2_rtne(a0.x, a0.y); af.u[1] = pack2_rtne(a0.z, a0.w);
        af.u[2] = pack2_rtne(a1.x, a1.y); af.u[3] = pack2_rtne(a1.z, a1.w);
#pragma unroll
        for (int c = 0; c < 2; ++c) {
            int o = (wid * 2 + c) * 16 + r;
            short8 bf = *(const short8*)&wbf[o][kk * 32 + q * 8];
            acc[c] = __builtin_amdgcn_mfma_f32_16x16x32_bf16(af.s8, bf, acc[c], 0, 0, 0);
        }
    }
#pragma unroll
    for (int c = 0; c < 2; ++c) {
        int o = (wid * 2 + c) * 16 + r;
        unsigned int u2[2];
        u2[0] = pack2_rtne(acc[c][0], acc[c][1]);
        u2[1] = pack2_rtne(acc[c][2], acc[c][3]);
        *(int2*)&hbf[o][q * 4] = *(const int2*)u2;
    }
    __syncthreads();

    if (t < 128) {
        int hd = t >> 5, d = t & 31;
        unsigned short* op = ht + ((size_t)(b * HH + hd) * DD + d) * NN + m_block;
        *(int4*)op       = *(const int4*)&hbf[t][0];
        *(int4*)(op + 8) = *(const int4*)&hbf[t][8];
    }
    {
        int m = t >> 4, sg = t & 15;
        const float* xp = x + (size_t)(m0g + m) * FF + sg * 8;
        float4 x0 = *(const float4*)xp;
        float4 x1 = *(const float4*)(xp + 4);
#pragma unroll
        for (int hd = 0; hd < 4; ++hd) {
            const float* vsp = &vs_s[hd][sg * 8];
            const float* vdp = &vd_s[hd][sg * 8];
            float es = x0.x * vsp[0] + x0.y * vsp[1] + x0.z * vsp[2] + x0.w * vsp[3]
                     + x1.x * vsp[4] + x1.y * vsp[5] + x1.z * vsp[6] + x1.w * vsp[7];
            float ed = x0.x * vdp[0] + x0.y * vdp[1] + x0.z * vdp[2] + x0.w * vdp[3]
                     + x1.x * vdp[4] + x1.y * vdp[5] + x1.z * vdp[6] + x1.w * vdp[7];
#pragma unroll
            for (int k = 1; k < 16; k <<= 1) {
                es += __shfl_xor(es, k);
                ed += __shfl_xor(ed, k);
            }
            if (sg == 0) {
                size_t eb = (size_t)(b * HH + hd) * NN + m_block + m;
                es_t[eb] = es * LOG2E;
                ed_t[eb] = ed * LOG2E;
            }
        }
    }
}

// ---------------- K2: fused masked-softmax attention + PV via MFMA (R5 structure)
#define HTS 2056
__global__ __launch_bounds__(1024) void k_attn(
        const unsigned short* __restrict__ ht,
        const unsigned int* __restrict__ bits,
        const float* __restrict__ es_t,
        const float* __restrict__ ed_t,
        float* __restrict__ out) {
    __shared__ unsigned short hb[DD * HTS];   // 128.5 KB
    __shared__ float ep[NN * 2];               // 16 KB
    int t = threadIdx.x;
    int n0 = blockIdx.x * 128;
    int bh = blockIdx.y;
    int b = bh >> 2, head = bh & 3;

    int wid = t >> 6, lane = t & 63;
    int q = lane >> 4, r = lane & 15;
    int qo = q * 8;
    int half = wid >> 3, wsub = wid & 7;
    int n_l = wsub * 16 + r;

    {
        float2 v = ((const float2*)(ed_t + (size_t)bh * NN))[t];
        float4 o;
        o.x = exp2_fast(v.x); o.y = exp2_fast(NEG_SLOPE * v.x);
        o.z = exp2_fast(v.y); o.w = exp2_fast(NEG_SLOPE * v.y);
        ((float4*)ep)[t] = o;
    }
    {
        const unsigned short* htp = ht + (size_t)bh * DD * NN;
#pragma unroll
        for (int k = 0; k < 8; ++k) {
            int qq = t + k * 1024;
            int d = qq >> 8, cm = qq & 255;
            int4 v = *(const int4*)(htp + (size_t)d * NN + cm * 8);
            *(int4*)&hb[d * HTS + cm * 8] = v;
        }
    }
    int4 bw[8];
    {
        const int4* bp = (const int4*)(bits + (size_t)(n0 + n_l) * 64 + half * 32);
#pragma unroll
        for (int g = 0; g < 8; ++g) bw[g] = bp[g];
    }
    float esv = es_t[(size_t)bh * NN + n0 + n_l];
    floatx2 es2 = {exp2_fast(esv), exp2_fast(NEG_SLOPE * esv)};
    __syncthreads();

    floatx4 acc0 = {0.f, 0.f, 0.f, 0.f};
    floatx4 acc1 = {0.f, 0.f, 0.f, 0.f};
    floatx4 accd = {0.f, 0.f, 0.f, 0.f};
    union { short8 s8; int i[4]; } ones;
    ones.i[0] = 0x3F803F80; ones.i[1] = 0x3F803F80;
    ones.i[2] = 0x3F803F80; ones.i[3] = 0x3F803F80;

    const float* eph = ep + half * 2048;
    const unsigned short* hrow0 = &hb[r * HTS + half * 1024 + qo];
    const unsigned short* hrow1 = hrow0 + 16 * HTS;

#pragma unroll
    for (int g = 0; g < 8; ++g) {
#pragma unroll
        for (int c = 0; c < 4; ++c) {
            unsigned int word = (unsigned int)((&bw[g].x)[c]);
            int mb = (g * 4 + c) * 32;
            unsigned int wq = word >> qo;
            const float* pbase = eph + (mb + qo) * 2;
            union { short8 s8; int i[4]; } af;
#pragma unroll
            for (int jp = 0; jp < 4; ++jp) {
                float4 d2 = *(const float4*)(pbase + jp * 4);
                floatx2 p0 = es2 * (floatx2){d2.x, d2.y};
                floatx2 p1 = es2 * (floatx2){d2.z, d2.w};
                float w0 = fmaxf(p0.x, p0.y);
                float w1 = fmaxf(p1.x, p1.y);
                int m0 = bit_mask(wq, 2 * jp);
                int m1 = bit_mask(wq, 2 * jp + 1);
                w0 = __uint_as_float(__float_as_uint(w0) & (unsigned int)m0);
                w1 = __uint_as_float(__float_as_uint(w1) & (unsigned int)m1);
                af.i[jp] = __builtin_amdgcn_perm(__float_as_uint(w1),
                                                 __float_as_uint(w0),
                                                 0x07060302u);
            }
            short8 b0 = *(const short8*)(hrow0 + mb);
            short8 b1 = *(const short8*)(hrow1 + mb);
            acc0 = __builtin_amdgcn_mfma_f32_16x16x32_bf16(af.s8, b0, acc0, 0, 0, 0);
            acc1 = __builtin_amdgcn_mfma_f32_16x16x32_bf16(af.s8, b1, acc1, 0, 0, 0);
            accd = __builtin_amdgcn_mfma_f32_16x16x32_bf16(af.s8, ones.s8, accd, 0, 0, 0);
        }
    }

    __syncthreads();
    float* scr = (float*)hb;
    if (wid >= 8) {
        int base = ((wid - 8) * 64 + lane) * 12;
        *(floatx4*)&scr[base + 0] = acc0;
        *(floatx4*)&scr[base + 4] = acc1;
        *(floatx4*)&scr[base + 8] = accd;
    }
    __syncthreads();
    if (wid < 8) {
        int base = (wid * 64 + lane) * 12;
        floatx4 p0 = *(const floatx4*)&scr[base + 0];
        floatx4 p1 = *(const floatx4*)&scr[base + 4];
        floatx4 pd = *(const floatx4*)&scr[base + 8];
#pragma unroll
        for (int k = 0; k < 4; ++k) {
            acc0[k] += p0[k]; acc1[k] += p1[k]; accd[k] += pd[k];
        }
#pragma unroll
        for (int reg = 0; reg < 4; ++reg) {
            int nrow = n0 + wsub * 16 + q * 4 + reg;
            float inv = 1.0f / accd[reg];
            float* op = out + ((size_t)(b * NN + nrow)) * FF + head * DD;
            op[r]      = acc0[reg] * inv;
            op[16 + r] = acc1[reg] * inv;
        }
    }
}

extern "C" void kernel_launch(void* const* d_in, const int* in_sizes, int n_in,
                              void* d_out, int out_size, void* d_ws, size_t ws_size,
                              hipStream_t stream) {
    const float* x     = (const float*)d_in[0];
    const int*   adj   = (const int*)d_in[1];
    const float* W     = (const float*)d_in[2];
    const float* a_src = (const float*)d_in[3];
    const float* a_dst = (const float*)d_in[4];
    float* out = (float*)d_out;

    float* es_t = (float*)d_ws;                                // 32,768 f
    float* ed_t = es_t + (size_t)BB * HH * NN;                 // 32,768 f
    unsigned int* bits = (unsigned int*)(ed_t + (size_t)BB * HH * NN);     // 131,072 u32
    unsigned short* ht = (unsigned short*)(bits + (size_t)NN * (NN / 32)); // 2,097,152 bf16

    hipLaunchKernelGGL(k_prep, dim3(1024), dim3(256), 0, stream,
                       x, W, a_src, a_dst, adj, ht, es_t, ed_t, bits);
    // MEASUREMENT ROUND: k_attn launched 3x (idempotent — fully overwrites
    // d_out with identical values). dur delta vs R10 = 2 x T_attn.
    hipLaunchKernelGGL(k_attn, dim3(NN / 128, BB * HH), dim3(1024), 0, stream,
                       ht, bits, es_t, ed_t, out);
    hipLaunchKernelGGL(k_attn, dim3(NN / 128, BB * HH), dim3(1024), 0, stream,
                       ht, bits, es_t, ed_t, out);
    hipLaunchKernelGGL(k_attn, dim3(NN / 128, BB * HH), dim3(1024), 0, stream,
                       ht, bits, es_t, ed_t, out);
}

// Round 12
// 123.587 us; speedup vs baseline: 1.1428x; 1.1428x over previous
//
#include <hip/hip_runtime.h>
#include <math.h>

#define BB 4
#define NN 2048
#define FF 128
#define HH 4
#define DD 32
#define NEG_SLOPE 0.2f
#define LOG2E 1.4426950408889634f

typedef __attribute__((ext_vector_type(8))) short short8;
typedef __attribute__((ext_vector_type(4))) float floatx4;
typedef __attribute__((ext_vector_type(2))) float floatx2;

__device__ __forceinline__ float exp2_fast(float x) {
#if __has_builtin(__builtin_amdgcn_exp2f)
    return __builtin_amdgcn_exp2f(x);
#else
    return exp2f(x);
#endif
}

__device__ __forceinline__ int bit_mask(unsigned int w, int bit) {
#if __has_builtin(__builtin_amdgcn_sbfe)
    return __builtin_amdgcn_sbfe((int)w, bit, 1);    // v_bfe_i32: 0 or -1
#else
    return ((int)(w << (31 - bit))) >> 31;
#endif
}

__device__ __forceinline__ unsigned short to_bf16(float f) {
    unsigned int ui = __float_as_uint(f);
    ui += 0x7FFFu + ((ui >> 16) & 1u);   // RTNE
    return (unsigned short)(ui >> 16);
}

// pack two fp32 -> one u32 holding (bf16(hi)<<16 | bf16(lo)), RTNE
__device__ __forceinline__ unsigned int pack2_rtne(float lo, float hi) {
    unsigned int ul = __float_as_uint(lo); ul += 0x7FFFu + ((ul >> 16) & 1u);
    unsigned int uh = __float_as_uint(hi); uh += 0x7FFFu + ((uh >> 16) & 1u);
    return (ul >> 16) | (uh & 0xFFFF0000u);
}

// ---------------- K1: prep = {MFMA gemm_fused (blocks 0..511), pack_adj (512..1023)}
__global__ __launch_bounds__(256) void k_prep(const float* __restrict__ x,
                                              const float* __restrict__ W,
                                              const float* __restrict__ a_src,
                                              const float* __restrict__ a_dst,
                                              const int* __restrict__ adj,
                                              unsigned short* __restrict__ ht,
                                              float* __restrict__ es_t,
                                              float* __restrict__ ed_t,
                                              unsigned int* __restrict__ bits) {
    __shared__ unsigned short wbf[128][144];   // 36 KB, W as bf16 [o][i]
    __shared__ unsigned short hbf[128][24];    // 6 KB, h^T as bf16 [o][m_local]
    __shared__ float vs_s[HH][FF], vd_s[HH][FF];   // 4 KB
    __shared__ float as_s[FF], ad_s[FF];           // 1 KB
    int t = threadIdx.x;

    if (blockIdx.x >= 512) {
        // ---- pack_adj ----
        int idx = (blockIdx.x - 512) * 256 + t;
        int n = idx >> 6, w = idx & 63;
        const int4* base = (const int4*)(adj + (size_t)n * NN + w * 32);
        unsigned int word = 0;
#pragma unroll
        for (int q = 0; q < 8; ++q) {
            int4 a = base[q];
            word |= ((unsigned int)(a.x & 1)) << (q * 4 + 0);
            word |= ((unsigned int)(a.y & 1)) << (q * 4 + 1);
            word |= ((unsigned int)(a.z & 1)) << (q * 4 + 2);
            word |= ((unsigned int)(a.w & 1)) << (q * 4 + 3);
        }
        bits[idx] = word;
        return;
    }

    int m0g = blockIdx.x * 16;
    int b = m0g >> 11;
    int m_block = m0g & 2047;

    if (t < FF) { as_s[t] = a_src[t]; ad_s[t] = a_dst[t]; }
    // stage W -> bf16 LDS: 2048 chunks of 8 shorts
#pragma unroll
    for (int k = 0; k < 8; ++k) {
        int idx = t + k * 256;
        int row = idx >> 4, ch = idx & 15;
        const float* wp = W + (size_t)row * FF + ch * 8;
        float4 v0 = *(const float4*)wp;
        float4 v1 = *(const float4*)(wp + 4);
        unsigned int u[4];
        u[0] = pack2_rtne(v0.x, v0.y); u[1] = pack2_rtne(v0.z, v0.w);
        u[2] = pack2_rtne(v1.x, v1.y); u[3] = pack2_rtne(v1.z, v1.w);
        *(int4*)&wbf[row][ch * 8] = *(const int4*)u;
    }
    __syncthreads();

    // per-head column sums: vs[h][i] = sum_d W[h*32+d][i]*a_src[h][d]
    {
        int i = t & 127;
        float acc4[4] = {0.f, 0.f, 0.f, 0.f};
        if (t < 128) {
            for (int o = 0; o < 128; ++o) {
                float wv = __uint_as_float(((unsigned int)wbf[o][i]) << 16);
                acc4[o >> 5] += wv * as_s[o];
            }
#pragma unroll
            for (int hd = 0; hd < 4; ++hd) vs_s[hd][i] = acc4[hd];
        } else {
            for (int o = 0; o < 128; ++o) {
                float wv = __uint_as_float(((unsigned int)wbf[o][i]) << 16);
                acc4[o >> 5] += wv * ad_s[o];
            }
#pragma unroll
            for (int hd = 0; hd < 4; ++hd) vd_s[hd][i] = acc4[hd];
        }
    }

    // MFMA: h[m0g..+15][0..127]
    int wid = t >> 6, lane = t & 63;
    int r = lane & 15, q = lane >> 4;
    floatx4 acc[2] = {{0.f,0.f,0.f,0.f},{0.f,0.f,0.f,0.f}};
    const float* xrow = x + (size_t)(m0g + r) * FF + q * 8;
#pragma unroll
    for (int kk = 0; kk < 4; ++kk) {
        float4 a0 = *(const float4*)(xrow + kk * 32);
        float4 a1 = *(const float4*)(xrow + kk * 32 + 4);
        union { short8 s8; unsigned int u[4]; } af;
        af.u[0] = pack2_rtne(a0.x, a0.y); af.u[1] = pack2_rtne(a0.z, a0.w);
        af.u[2] = pack2_rtne(a1.x, a1.y); af.u[3] = pack2_rtne(a1.z, a1.w);
#pragma unroll
        for (int c = 0; c < 2; ++c) {
            int o = (wid * 2 + c) * 16 + r;
            short8 bf = *(const short8*)&wbf[o][kk * 32 + q * 8];
            acc[c] = __builtin_amdgcn_mfma_f32_16x16x32_bf16(af.s8, bf, acc[c], 0, 0, 0);
        }
    }
#pragma unroll
    for (int c = 0; c < 2; ++c) {
        int o = (wid * 2 + c) * 16 + r;
        unsigned int u2[2];
        u2[0] = pack2_rtne(acc[c][0], acc[c][1]);
        u2[1] = pack2_rtne(acc[c][2], acc[c][3]);
        *(int2*)&hbf[o][q * 4] = *(const int2*)u2;
    }
    __syncthreads();

    if (t < 128) {
        int hd = t >> 5, d = t & 31;
        unsigned short* op = ht + ((size_t)(b * HH + hd) * DD + d) * NN + m_block;
        *(int4*)op       = *(const int4*)&hbf[t][0];
        *(int4*)(op + 8) = *(const int4*)&hbf[t][8];
    }
    {
        int m = t >> 4, sg = t & 15;
        const float* xp = x + (size_t)(m0g + m) * FF + sg * 8;
        float4 x0 = *(const float4*)xp;
        float4 x1 = *(const float4*)(xp + 4);
#pragma unroll
        for (int hd = 0; hd < 4; ++hd) {
            const float* vsp = &vs_s[hd][sg * 8];
            const float* vdp = &vd_s[hd][sg * 8];
            float es = x0.x * vsp[0] + x0.y * vsp[1] + x0.z * vsp[2] + x0.w * vsp[3]
                     + x1.x * vsp[4] + x1.y * vsp[5] + x1.z * vsp[6] + x1.w * vsp[7];
            float ed = x0.x * vdp[0] + x0.y * vdp[1] + x0.z * vdp[2] + x0.w * vdp[3]
                     + x1.x * vdp[4] + x1.y * vdp[5] + x1.z * vdp[6] + x1.w * vdp[7];
#pragma unroll
            for (int k = 1; k < 16; k <<= 1) {
                es += __shfl_xor(es, k);
                ed += __shfl_xor(ed, k);
            }
            if (sg == 0) {
                size_t eb = (size_t)(b * HH + hd) * NN + m_block + m;
                es_t[eb] = es * LOG2E;
                ed_t[eb] = ed * LOG2E;
            }
        }
    }
}

// ---------------- K2: fused masked-softmax attention + PV via MFMA (R5 structure)
#define HTS 2056
__global__ __launch_bounds__(1024) void k_attn(
        const unsigned short* __restrict__ ht,
        const unsigned int* __restrict__ bits,
        const float* __restrict__ es_t,
        const float* __restrict__ ed_t,
        float* __restrict__ out) {
    __shared__ unsigned short hb[DD * HTS];   // 128.5 KB
    __shared__ float ep[NN * 2];               // 16 KB
    int t = threadIdx.x;
    int n0 = blockIdx.x * 128;
    int bh = blockIdx.y;
    int b = bh >> 2, head = bh & 3;

    int wid = t >> 6, lane = t & 63;
    int q = lane >> 4, r = lane & 15;
    int qo = q * 8;
    int half = wid >> 3, wsub = wid & 7;
    int n_l = wsub * 16 + r;

    {
        float2 v = ((const float2*)(ed_t + (size_t)bh * NN))[t];
        float4 o;
        o.x = exp2_fast(v.x); o.y = exp2_fast(NEG_SLOPE * v.x);
        o.z = exp2_fast(v.y); o.w = exp2_fast(NEG_SLOPE * v.y);
        ((float4*)ep)[t] = o;
    }
    {
        const unsigned short* htp = ht + (size_t)bh * DD * NN;
#pragma unroll
        for (int k = 0; k < 8; ++k) {
            int qq = t + k * 1024;
            int d = qq >> 8, cm = qq & 255;
            int4 v = *(const int4*)(htp + (size_t)d * NN + cm * 8);
            *(int4*)&hb[d * HTS + cm * 8] = v;
        }
    }
    int4 bw[8];
    {
        const int4* bp = (const int4*)(bits + (size_t)(n0 + n_l) * 64 + half * 32);
#pragma unroll
        for (int g = 0; g < 8; ++g) bw[g] = bp[g];
    }
    float esv = es_t[(size_t)bh * NN + n0 + n_l];
    floatx2 es2 = {exp2_fast(esv), exp2_fast(NEG_SLOPE * esv)};
    __syncthreads();

    floatx4 acc0 = {0.f, 0.f, 0.f, 0.f};
    floatx4 acc1 = {0.f, 0.f, 0.f, 0.f};
    floatx4 accd = {0.f, 0.f, 0.f, 0.f};
    union { short8 s8; int i[4]; } ones;
    ones.i[0] = 0x3F803F80; ones.i[1] = 0x3F803F80;
    ones.i[2] = 0x3F803F80; ones.i[3] = 0x3F803F80;

    const float* eph = ep + half * 2048;
    const unsigned short* hrow0 = &hb[r * HTS + half * 1024 + qo];
    const unsigned short* hrow1 = hrow0 + 16 * HTS;

#pragma unroll
    for (int g = 0; g < 8; ++g) {
#pragma unroll
        for (int c = 0; c < 4; ++c) {
            unsigned int word = (unsigned int)((&bw[g].x)[c]);
            int mb = (g * 4 + c) * 32;
            unsigned int wq = word >> qo;
            const float* pbase = eph + (mb + qo) * 2;
            union { short8 s8; int i[4]; } af;
#pragma unroll
            for (int jp = 0; jp < 4; ++jp) {
                float4 d2 = *(const float4*)(pbase + jp * 4);
                floatx2 p0 = es2 * (floatx2){d2.x, d2.y};
                floatx2 p1 = es2 * (floatx2){d2.z, d2.w};
                float w0 = fmaxf(p0.x, p0.y);
                float w1 = fmaxf(p1.x, p1.y);
                int m0 = bit_mask(wq, 2 * jp);
                int m1 = bit_mask(wq, 2 * jp + 1);
                w0 = __uint_as_float(__float_as_uint(w0) & (unsigned int)m0);
                w1 = __uint_as_float(__float_as_uint(w1) & (unsigned int)m1);
                af.i[jp] = __builtin_amdgcn_perm(__float_as_uint(w1),
                                                 __float_as_uint(w0),
                                                 0x07060302u);
            }
            short8 b0 = *(const short8*)(hrow0 + mb);
            short8 b1 = *(const short8*)(hrow1 + mb);
            acc0 = __builtin_amdgcn_mfma_f32_16x16x32_bf16(af.s8, b0, acc0, 0, 0, 0);
            acc1 = __builtin_amdgcn_mfma_f32_16x16x32_bf16(af.s8, b1, acc1, 0, 0, 0);
            accd = __builtin_amdgcn_mfma_f32_16x16x32_bf16(af.s8, ones.s8, accd, 0, 0, 0);
        }
    }

    __syncthreads();
    float* scr = (float*)hb;
    if (wid >= 8) {
        int base = ((wid - 8) * 64 + lane) * 12;
        *(floatx4*)&scr[base + 0] = acc0;
        *(floatx4*)&scr[base + 4] = acc1;
        *(floatx4*)&scr[base + 8] = accd;
    }
    __syncthreads();
    if (wid < 8) {
        int base = (wid * 64 + lane) * 12;
        floatx4 p0 = *(const floatx4*)&scr[base + 0];
        floatx4 p1 = *(const floatx4*)&scr[base + 4];
        floatx4 pd = *(const floatx4*)&scr[base + 8];
#pragma unroll
        for (int k = 0; k < 4; ++k) {
            acc0[k] += p0[k]; acc1[k] += p1[k]; accd[k] += pd[k];
        }
#pragma unroll
        for (int reg = 0; reg < 4; ++reg) {
            int nrow = n0 + wsub * 16 + q * 4 + reg;
            float inv = 1.0f / accd[reg];
            float* op = out + ((size_t)(b * NN + nrow)) * FF + head * DD;
            op[r]      = acc0[reg] * inv;
            op[16 + r] = acc1[reg] * inv;
        }
    }
}

extern "C" void kernel_launch(void* const* d_in, const int* in_sizes, int n_in,
                              void* d_out, int out_size, void* d_ws, size_t ws_size,
                              hipStream_t stream) {
    const float* x     = (const float*)d_in[0];
    const int*   adj   = (const int*)d_in[1];
    const float* W     = (const float*)d_in[2];
    const float* a_src = (const float*)d_in[3];
    const float* a_dst = (const float*)d_in[4];
    float* out = (float*)d_out;

    float* es_t = (float*)d_ws;                                // 32,768 f
    float* ed_t = es_t + (size_t)BB * HH * NN;                 // 32,768 f
    unsigned int* bits = (unsigned int*)(ed_t + (size_t)BB * HH * NN);     // 131,072 u32
    unsigned short* ht = (unsigned short*)(bits + (size_t)NN * (NN / 32)); // 2,097,152 bf16

    // MEASUREMENT ROUND: k_prep launched 3x (idempotent — pure function of
    // d_in, fully overwrites ht/es_t/ed_t/bits). prep = (dur - 121.5)/2.
    hipLaunchKernelGGL(k_prep, dim3(1024), dim3(256), 0, stream,
                       x, W, a_src, a_dst, adj, ht, es_t, ed_t, bits);
    hipLaunchKernelGGL(k_prep, dim3(1024), dim3(256), 0, stream,
                       x, W, a_src, a_dst, adj, ht, es_t, ed_t, bits);
    hipLaunchKernelGGL(k_prep, dim3(1024), dim3(256), 0, stream,
                       x, W, a_src, a_dst, adj, ht, es_t, ed_t, bits);
    hipLaunchKernelGGL(k_attn, dim3(NN / 128, BB * HH), dim3(1024), 0, stream,
                       ht, bits, es_t, ed_t, out);
}

// Round 13
// 103.940 us; speedup vs baseline: 1.3588x; 1.1890x over previous
//
#include <hip/hip_runtime.h>
#include <math.h>

#define BB 4
#define NN 2048
#define FF 128
#define HH 4
#define DD 32
#define NEG_SLOPE 0.2f
#define LOG2E 1.4426950408889634f

typedef __attribute__((ext_vector_type(8))) short short8;
typedef __attribute__((ext_vector_type(4))) float floatx4;
typedef __attribute__((ext_vector_type(2))) float floatx2;

__device__ __forceinline__ float exp2_fast(float x) {
#if __has_builtin(__builtin_amdgcn_exp2f)
    return __builtin_amdgcn_exp2f(x);
#else
    return exp2f(x);
#endif
}

__device__ __forceinline__ int bit_mask(unsigned int w, int bit) {
#if __has_builtin(__builtin_amdgcn_sbfe)
    return __builtin_amdgcn_sbfe((int)w, bit, 1);    // v_bfe_i32: 0 or -1
#else
    return ((int)(w << (31 - bit))) >> 31;
#endif
}

__device__ __forceinline__ unsigned short to_bf16(float f) {
    unsigned int ui = __float_as_uint(f);
    ui += 0x7FFFu + ((ui >> 16) & 1u);   // RTNE
    return (unsigned short)(ui >> 16);
}

// pack two fp32 -> one u32 holding (bf16(hi)<<16 | bf16(lo)), RTNE
__device__ __forceinline__ unsigned int pack2_rtne(float lo, float hi) {
    unsigned int ul = __float_as_uint(lo); ul += 0x7FFFu + ((ul >> 16) & 1u);
    unsigned int uh = __float_as_uint(hi); uh += 0x7FFFu + ((uh >> 16) & 1u);
    return (ul >> 16) | (uh & 0xFFFF0000u);
}

// pack (exp2(e), exp2(0.2e)) as (bf16(Ed_p)<<16 | bf16(Ed_n))  [R7-proven]
__device__ __forceinline__ unsigned int pack_pair(float e) {
    unsigned int p = to_bf16(exp2_fast(e));
    unsigned int n = to_bf16(exp2_fast(NEG_SLOPE * e));
    return (p << 16) | n;
}

// ---------------- K1: prep (R10 verbatim) = {MFMA gemm_fused 0..511, pack_adj 512..1023}
__global__ __launch_bounds__(256) void k_prep(const float* __restrict__ x,
                                              const float* __restrict__ W,
                                              const float* __restrict__ a_src,
                                              const float* __restrict__ a_dst,
                                              const int* __restrict__ adj,
                                              unsigned short* __restrict__ ht,
                                              float* __restrict__ es_t,
                                              float* __restrict__ ed_t,
                                              unsigned int* __restrict__ bits) {
    __shared__ unsigned short wbf[128][144];   // 36 KB, W as bf16 [o][i]
    __shared__ unsigned short hbf[128][24];    // 6 KB, h^T as bf16 [o][m_local]
    __shared__ float vs_s[HH][FF], vd_s[HH][FF];   // 4 KB
    __shared__ float as_s[FF], ad_s[FF];           // 1 KB
    int t = threadIdx.x;

    if (blockIdx.x >= 512) {
        // ---- pack_adj ----
        int idx = (blockIdx.x - 512) * 256 + t;
        int n = idx >> 6, w = idx & 63;
        const int4* base = (const int4*)(adj + (size_t)n * NN + w * 32);
        unsigned int word = 0;
#pragma unroll
        for (int q = 0; q < 8; ++q) {
            int4 a = base[q];
            word |= ((unsigned int)(a.x & 1)) << (q * 4 + 0);
            word |= ((unsigned int)(a.y & 1)) << (q * 4 + 1);
            word |= ((unsigned int)(a.z & 1)) << (q * 4 + 2);
            word |= ((unsigned int)(a.w & 1)) << (q * 4 + 3);
        }
        bits[idx] = word;
        return;
    }

    int m0g = blockIdx.x * 16;
    int b = m0g >> 11;
    int m_block = m0g & 2047;

    if (t < FF) { as_s[t] = a_src[t]; ad_s[t] = a_dst[t]; }
#pragma unroll
    for (int k = 0; k < 8; ++k) {
        int idx = t + k * 256;
        int row = idx >> 4, ch = idx & 15;
        const float* wp = W + (size_t)row * FF + ch * 8;
        float4 v0 = *(const float4*)wp;
        float4 v1 = *(const float4*)(wp + 4);
        unsigned int u[4];
        u[0] = pack2_rtne(v0.x, v0.y); u[1] = pack2_rtne(v0.z, v0.w);
        u[2] = pack2_rtne(v1.x, v1.y); u[3] = pack2_rtne(v1.z, v1.w);
        *(int4*)&wbf[row][ch * 8] = *(const int4*)u;
    }
    __syncthreads();

    // per-head column sums: vs[h][i] = sum_d W[h*32+d][i]*a_src[h][d]
    {
        int i = t & 127;
        float acc4[4] = {0.f, 0.f, 0.f, 0.f};
        if (t < 128) {
            for (int o = 0; o < 128; ++o) {
                float wv = __uint_as_float(((unsigned int)wbf[o][i]) << 16);
                acc4[o >> 5] += wv * as_s[o];
            }
#pragma unroll
            for (int hd = 0; hd < 4; ++hd) vs_s[hd][i] = acc4[hd];
        } else {
            for (int o = 0; o < 128; ++o) {
                float wv = __uint_as_float(((unsigned int)wbf[o][i]) << 16);
                acc4[o >> 5] += wv * ad_s[o];
            }
#pragma unroll
            for (int hd = 0; hd < 4; ++hd) vd_s[hd][i] = acc4[hd];
        }
    }

    // MFMA: h[m0g..+15][0..127]
    int wid = t >> 6, lane = t & 63;
    int r = lane & 15, q = lane >> 4;
    floatx4 acc[2] = {{0.f,0.f,0.f,0.f},{0.f,0.f,0.f,0.f}};
    const float* xrow = x + (size_t)(m0g + r) * FF + q * 8;
#pragma unroll
    for (int kk = 0; kk < 4; ++kk) {
        float4 a0 = *(const float4*)(xrow + kk * 32);
        float4 a1 = *(const float4*)(xrow + kk * 32 + 4);
        union { short8 s8; unsigned int u[4]; } af;
        af.u[0] = pack2_rtne(a0.x, a0.y); af.u[1] = pack2_rtne(a0.z, a0.w);
        af.u[2] = pack2_rtne(a1.x, a1.y); af.u[3] = pack2_rtne(a1.z, a1.w);
#pragma unroll
        for (int c = 0; c < 2; ++c) {
            int o = (wid * 2 + c) * 16 + r;
            short8 bf = *(const short8*)&wbf[o][kk * 32 + q * 8];
            acc[c] = __builtin_amdgcn_mfma_f32_16x16x32_bf16(af.s8, bf, acc[c], 0, 0, 0);
        }
    }
#pragma unroll
    for (int c = 0; c < 2; ++c) {
        int o = (wid * 2 + c) * 16 + r;
        unsigned int u2[2];
        u2[0] = pack2_rtne(acc[c][0], acc[c][1]);
        u2[1] = pack2_rtne(acc[c][2], acc[c][3]);
        *(int2*)&hbf[o][q * 4] = *(const int2*)u2;
    }
    __syncthreads();

    if (t < 128) {
        int hd = t >> 5, d = t & 31;
        unsigned short* op = ht + ((size_t)(b * HH + hd) * DD + d) * NN + m_block;
        *(int4*)op       = *(const int4*)&hbf[t][0];
        *(int4*)(op + 8) = *(const int4*)&hbf[t][8];
    }
    {
        int m = t >> 4, sg = t & 15;
        const float* xp = x + (size_t)(m0g + m) * FF + sg * 8;
        float4 x0 = *(const float4*)xp;
        float4 x1 = *(const float4*)(xp + 4);
#pragma unroll
        for (int hd = 0; hd < 4; ++hd) {
            const float* vsp = &vs_s[hd][sg * 8];
            const float* vdp = &vd_s[hd][sg * 8];
            float es = x0.x * vsp[0] + x0.y * vsp[1] + x0.z * vsp[2] + x0.w * vsp[3]
                     + x1.x * vsp[4] + x1.y * vsp[5] + x1.z * vsp[6] + x1.w * vsp[7];
            float ed = x0.x * vdp[0] + x0.y * vdp[1] + x0.z * vdp[2] + x0.w * vdp[3]
                     + x1.x * vdp[4] + x1.y * vdp[5] + x1.z * vdp[6] + x1.w * vdp[7];
#pragma unroll
            for (int k = 1; k < 16; k <<= 1) {
                es += __shfl_xor(es, k);
                ed += __shfl_xor(ed, k);
            }
            if (sg == 0) {
                size_t eb = (size_t)(b * HH + hd) * NN + m_block + m;
                es_t[eb] = es * LOG2E;
                ed_t[eb] = ed * LOG2E;
            }
        }
    }
}

// ---------------- K2: attn (R5/R10 structure; ONE change: ep packed bf16 pairs)
// Per iter LDS: 2 int4 ep reads + 2 b128 hb reads (was 4+2).
#define HTS 2056
__global__ __launch_bounds__(1024) void k_attn(
        const unsigned short* __restrict__ ht,
        const unsigned int* __restrict__ bits,
        const float* __restrict__ es_t,
        const float* __restrict__ ed_t,
        float* __restrict__ out) {
    __shared__ unsigned short hb[DD * HTS];   // 128.5 KB
    __shared__ unsigned int epk[NN];           // 8 KB packed (Ed_p|Ed_n)
    int t = threadIdx.x;
    int n0 = blockIdx.x * 128;
    int bh = blockIdx.y;
    int b = bh >> 2, head = bh & 3;

    int wid = t >> 6, lane = t & 63;
    int q = lane >> 4, r = lane & 15;
    int qo = q * 8;
    int half = wid >> 3, wsub = wid & 7;
    int n_l = wsub * 16 + r;

    // stage packed Ed pairs: 2 m per thread
    {
        float2 v = ((const float2*)(ed_t + (size_t)bh * NN))[t];
        uint2 o = {pack_pair(v.x), pack_pair(v.y)};
        ((uint2*)epk)[t] = o;
    }
    // stage full ht slice: 8192 int4 chunks
    {
        const unsigned short* htp = ht + (size_t)bh * DD * NN;
#pragma unroll
        for (int k = 0; k < 8; ++k) {
            int qq = t + k * 1024;
            int d = qq >> 8, cm = qq & 255;
            int4 v = *(const int4*)(htp + (size_t)d * NN + cm * 8);
            *(int4*)&hb[d * HTS + cm * 8] = v;
        }
    }
    int4 bw[8];
    {
        const int4* bp = (const int4*)(bits + (size_t)(n0 + n_l) * 64 + half * 32);
#pragma unroll
        for (int g = 0; g < 8; ++g) bw[g] = bp[g];
    }
    float esv = es_t[(size_t)bh * NN + n0 + n_l];
    floatx2 es2 = {exp2_fast(esv), exp2_fast(NEG_SLOPE * esv)};
    __syncthreads();

    floatx4 acc0 = {0.f, 0.f, 0.f, 0.f};
    floatx4 acc1 = {0.f, 0.f, 0.f, 0.f};
    floatx4 accd = {0.f, 0.f, 0.f, 0.f};
    union { short8 s8; int i[4]; } ones;
    ones.i[0] = 0x3F803F80; ones.i[1] = 0x3F803F80;
    ones.i[2] = 0x3F803F80; ones.i[3] = 0x3F803F80;

    const unsigned int* eph = epk + half * 1024;
    const unsigned short* hrow0 = &hb[r * HTS + half * 1024 + qo];
    const unsigned short* hrow1 = hrow0 + 16 * HTS;

#pragma unroll
    for (int g = 0; g < 8; ++g) {
#pragma unroll
        for (int c = 0; c < 4; ++c) {
            unsigned int word = (unsigned int)((&bw[g].x)[c]);
            int mb = (g * 4 + c) * 32;
            unsigned int wq = word >> qo;
            const uint4* pbase = (const uint4*)(eph + mb + qo);
            uint4 u0 = pbase[0];
            uint4 u1 = pbase[1];
            union { short8 s8; int i[4]; } af;
#pragma unroll
            for (int jp = 0; jp < 4; ++jp) {
                unsigned int c0 = (jp < 2) ? (&u0.x)[jp * 2]     : (&u1.x)[(jp - 2) * 2];
                unsigned int c1 = (jp < 2) ? (&u0.x)[jp * 2 + 1] : (&u1.x)[(jp - 2) * 2 + 1];
                floatx2 d0 = {__uint_as_float(c0 & 0xFFFF0000u),
                              __uint_as_float(c0 << 16)};
                floatx2 d1 = {__uint_as_float(c1 & 0xFFFF0000u),
                              __uint_as_float(c1 << 16)};
                floatx2 p0 = es2 * d0;
                floatx2 p1 = es2 * d1;
                float w0 = fmaxf(p0.x, p0.y);
                float w1 = fmaxf(p1.x, p1.y);
                int m0 = bit_mask(wq, 2 * jp);
                int m1 = bit_mask(wq, 2 * jp + 1);
                w0 = __uint_as_float(__float_as_uint(w0) & (unsigned int)m0);
                w1 = __uint_as_float(__float_as_uint(w1) & (unsigned int)m1);
                af.i[jp] = __builtin_amdgcn_perm(__float_as_uint(w1),
                                                 __float_as_uint(w0),
                                                 0x07060302u);
            }
            short8 b0 = *(const short8*)(hrow0 + mb);
            short8 b1 = *(const short8*)(hrow1 + mb);
            acc0 = __builtin_amdgcn_mfma_f32_16x16x32_bf16(af.s8, b0, acc0, 0, 0, 0);
            acc1 = __builtin_amdgcn_mfma_f32_16x16x32_bf16(af.s8, b1, acc1, 0, 0, 0);
            accd = __builtin_amdgcn_mfma_f32_16x16x32_bf16(af.s8, ones.s8, accd, 0, 0, 0);
        }
    }

    __syncthreads();
    float* scr = (float*)hb;
    if (wid >= 8) {
        int base = ((wid - 8) * 64 + lane) * 12;
        *(floatx4*)&scr[base + 0] = acc0;
        *(floatx4*)&scr[base + 4] = acc1;
        *(floatx4*)&scr[base + 8] = accd;
    }
    __syncthreads();
    if (wid < 8) {
        int base = (wid * 64 + lane) * 12;
        floatx4 p0 = *(const floatx4*)&scr[base + 0];
        floatx4 p1 = *(const floatx4*)&scr[base + 4];
        floatx4 pd = *(const floatx4*)&scr[base + 8];
#pragma unroll
        for (int k = 0; k < 4; ++k) {
            acc0[k] += p0[k]; acc1[k] += p1[k]; accd[k] += pd[k];
        }
#pragma unroll
        for (int reg = 0; reg < 4; ++reg) {
            int nrow = n0 + wsub * 16 + q * 4 + reg;
            float inv = 1.0f / accd[reg];
            float* op = out + ((size_t)(b * NN + nrow)) * FF + head * DD;
            op[r]      = acc0[reg] * inv;
            op[16 + r] = acc1[reg] * inv;
        }
    }
}

extern "C" void kernel_launch(void* const* d_in, const int* in_sizes, int n_in,
                              void* d_out, int out_size, void* d_ws, size_t ws_size,
                              hipStream_t stream) {
    const float* x     = (const float*)d_in[0];
    const int*   adj   = (const int*)d_in[1];
    const float* W     = (const float*)d_in[2];
    const float* a_src = (const float*)d_in[3];
    const float* a_dst = (const float*)d_in[4];
    float* out = (float*)d_out;

    float* es_t = (float*)d_ws;                                // 32,768 f
    float* ed_t = es_t + (size_t)BB * HH * NN;                 // 32,768 f
    unsigned int* bits = (unsigned int*)(ed_t + (size_t)BB * HH * NN);     // 131,072 u32
    unsigned short* ht = (unsigned short*)(bits + (size_t)NN * (NN / 32)); // 2,097,152 bf16

    hipLaunchKernelGGL(k_prep, dim3(1024), dim3(256), 0, stream,
                       x, W, a_src, a_dst, adj, ht, es_t, ed_t, bits);
    hipLaunchKernelGGL(k_attn, dim3(NN / 128, BB * HH), dim3(1024), 0, stream,
                       ht, bits, es_t, ed_t, out);
}